// Round 11
// baseline (38.579 us; speedup 1.0000x reference)
//
#include <hip/hip_runtime.h>
#include <hip/hip_bf16.h>
#include <math.h>

// PersistentHomology: out = std(dist, ddof=1) / (mean(dist) + 1e-8) over the
// 8192x8192 Euclidean distance matrix of 8192 fp32 points, D=128.
// S1 = sum(dist) via bf16-MFMA Gram tiles; S2 closed form (exact fp64):
// 2N*sum|x_i|^2 - 2*|sum_i x_i|^2.
// Round 11: A-slab-in-registers + B-stream. Block owns a 128-row i-slab
// (A held in 64 VGPR/wave for the FULL K=128), loops over 4-5 j-panels with
// double-buffered LDS B (issue-early stage under compute, r7-proven). Grid =
// 512 = exactly 2 blocks/CU (LDS 66KB, VGPR~190 @ (256,2)) -> zero tail.

#define NPTS   8192
#define DIM    128
#define TIL    128
#define NSLAB  (NPTS / TIL)                   // 64
#define NPAIR  (NSLAB * (NSLAB + 1) / 2)      // 2080 upper-tri pairs
#define NBLKS  512                            // 32 blocks x5 pairs + 480 x4
#define NPREP  (NPTS / 32)                    // 256 prep blocks
#define NTILES (NPTS / 128)                   // fp32 fallback path
#define NTOTSQ (NTILES * NTILES)

typedef __attribute__((ext_vector_type(8))) short short8;   // 8 bf16
typedef __attribute__((ext_vector_type(4))) float f32x4;    // MFMA accumulator

typedef const __attribute__((address_space(1))) void* gas_ptr;
typedef __attribute__((address_space(3))) void* las_ptr;

__device__ __forceinline__ void gload16(const void* g, void* l) {
    // DMA 16B/lane global->LDS; LDS dest = wave-uniform base + lane*16
    __builtin_amdgcn_global_load_lds((gas_ptr)g, (las_ptr)l, 16, 0, 0);
}
__device__ __forceinline__ float fsqrt(float x) {
    return __builtin_amdgcn_sqrtf(x);        // v_sqrt_f32
}

// ---- prep: fp32 -> bf16, fp32 norms, per-block fp32 column-sum partials ----
__global__ __launch_bounds__(256)
void ph_prep(const float* __restrict__ x, ushort* __restrict__ xb,
             float* __restrict__ sq, float* __restrict__ cs_part)
{
    __shared__ float xs[32][129];                  // padded: conflict-free col reads
    const int tid = threadIdx.x;
    const int rw  = tid >> 3;                      // 0..31 row-in-block
    const int row = blockIdx.x * 32 + rw;
    const int seg = tid & 7;                       // 16 elems per thread
    const float4* p = reinterpret_cast<const float4*>(x + (size_t)row * DIM + seg * 16);
    float v[16];
    {
        float4 a = p[0], b = p[1], c = p[2], d = p[3];
        v[0]=a.x; v[1]=a.y; v[2]=a.z; v[3]=a.w;  v[4]=b.x; v[5]=b.y; v[6]=b.z; v[7]=b.w;
        v[8]=c.x; v[9]=c.y; v[10]=c.z; v[11]=c.w; v[12]=d.x; v[13]=d.y; v[14]=d.z; v[15]=d.w;
    }
    float s = 0.f;
    ushort h[16];
#pragma unroll
    for (int j = 0; j < 16; ++j) {
        __hip_bfloat16 hb = __float2bfloat16(v[j]);
        h[j] = *reinterpret_cast<ushort*>(&hb);
        s = fmaf(v[j], v[j], s);
        xs[rw][seg * 16 + j] = v[j];
    }
    short8 o0, o1;
#pragma unroll
    for (int j = 0; j < 8; ++j) { o0[j] = (short)h[j]; o1[j] = (short)h[j+8]; }
    short8* dst = reinterpret_cast<short8*>(xb + (size_t)row * DIM + seg * 16);
    dst[0] = o0; dst[1] = o1;
    s += __shfl_xor(s, 1); s += __shfl_xor(s, 2); s += __shfl_xor(s, 4);
    if (seg == 0) sq[row] = s;
    __syncthreads();
    if (tid < DIM) {                               // column sums over 32 rows
        float c = 0.f;
#pragma unroll 8
        for (int r = 0; r < 32; ++r) c += xs[r][tid];
        cs_part[blockIdx.x * DIM + tid] = c;
    }
}

// ---- main: A-slab in regs, B-panel j-stream, dbuf LDS, 512 blocks ----
// B LDS layout: 128 rows x 256B, swizzled: phys = row*256 + (kb ^ ((row&7)<<4)).
// Stage writes linear (gload_lds); inverse swizzle applied on the GLOBAL source.
__global__ __launch_bounds__(256, 2)
void ph_gram(const ushort* __restrict__ xb, const float* __restrict__ sq,
             double* __restrict__ partials)
{
    const int b    = blockIdx.x;         // 0..NBLKS-1
    const int tid  = threadIdx.x;
    const int lane = tid & 63;
    const int wv   = tid >> 6;           // wave 0..3
    const int wr   = wv >> 1;            // row half of slab (0..1)
    const int wc   = wv & 1;             // col half of panel (0..1)

    __shared__ ushort Bbuf[2][TIL * DIM];   // 2 x 32 KB
    __shared__ double rr[4];

    // contiguous pair range: 2080 = 32*5 + 480*4
    const int pstart = 4 * b + (b < 32 ? b : 32);
    const int pcnt   = 4 + (b < 32 ? 1 : 0);

    // decode first pair p -> (si, tj), si <= tj ; T(r) = r*64 - r*(r-1)/2
    int p  = pstart;
    int si = (int)((129.0f - fsqrt((float)(16641 - 8 * p))) * 0.5f);
    while ((si + 1) * 64 - ((si + 1) * si) / 2 <= p) ++si;
    while (si * 64 - (si * (si - 1)) / 2 > p) --si;
    int tj = si + (p - (si * 64 - (si * (si - 1)) / 2));

    short8 af[4][4];     // A fragments: full K=128 of this wave's 64 rows (64 VGPR)
    float4 na4[4];       // row norms for the 16 (m,r) rows this lane touches

#define LOADA(s_)                                                             \
    {                                                                         \
        const char* ga = (const char*)xb +                                    \
            ((size_t)(s_) * TIL + wr * 64 + (lane & 15)) * 256;               \
        _Pragma("unroll")                                                     \
        for (int m = 0; m < 4; ++m)                                           \
            _Pragma("unroll")                                                 \
            for (int ks = 0; ks < 4; ++ks)                                    \
                af[m][ks] = *reinterpret_cast<const short8*>(                 \
                    ga + m * 16 * 256 + ks * 64 + (lane >> 4) * 16);          \
        const float* sa = sq + (s_) * TIL + wr * 64 + (lane >> 4) * 4;        \
        _Pragma("unroll")                                                     \
        for (int m = 0; m < 4; ++m)                                           \
            na4[m] = *reinterpret_cast<const float4*>(sa + m * 16);           \
    }

    // stage panel t_: 8 x gload16 per thread; linear LDS dest, pre-swz source
#define STAGEB(t_, buf_)                                                      \
    {                                                                         \
        const char* gb = (const char*)xb + (size_t)(t_) * TIL * 256;          \
        char* dst_ = (char*)(buf_);                                           \
        _Pragma("unroll")                                                     \
        for (int i = 0; i < 8; ++i) {                                         \
            const int row = i * 16 + (tid >> 4);                              \
            const int kbl = ((tid & 15) * 16) ^ ((row & 7) << 4);             \
            gload16(gb + (size_t)row * 256 + kbl, dst_ + i * 4096 + tid * 16);\
        }                                                                     \
    }

    f32x4 acc[4][4];
#define COMPUTEP(buf_)                                                        \
    {                                                                         \
        _Pragma("unroll")                                                     \
        for (int ks = 0; ks < 4; ++ks) {                                      \
            const int kb = ks * 64 + (lane >> 4) * 16;                        \
            short8 bfr[4];                                                    \
            _Pragma("unroll")                                                 \
            for (int n = 0; n < 4; ++n) {                                     \
                const int col = wc * 64 + n * 16 + (lane & 15);               \
                bfr[n] = *reinterpret_cast<const short8*>(                    \
                    (const char*)(buf_) + col * 256 + (kb ^ ((col & 7) << 4)));\
            }                                                                 \
            __builtin_amdgcn_s_setprio(1);                                    \
            _Pragma("unroll")                                                 \
            for (int m = 0; m < 4; ++m)                                       \
                _Pragma("unroll")                                             \
                for (int n = 0; n < 4; ++n)                                   \
                    acc[m][n] = __builtin_amdgcn_mfma_f32_16x16x32_bf16(      \
                        af[m][ks], bfr[n], acc[m][n], 0, 0, 0);               \
            __builtin_amdgcn_s_setprio(0);                                    \
        }                                                                     \
    }

    LOADA(si);
    STAGEB(tj, Bbuf[0]);
    __syncthreads();                     // prologue drain (once)

    int   asi = si, csi = si, ctj = tj, cur = 0;
    float sOa = 0.f, sOb = 0.f, sOc = 0.f, sOd = 0.f;   // off-diag (weight 2)
    float sD  = 0.f;                                     // diag (weight 1)

    for (int it = 0; it < pcnt; ++it) {
        // next pair indices (row-major walk of the upper triangle)
        int nsi = csi, ntj = ctj + 1;
        if (ntj == NSLAB) { ++nsi; ntj = nsi; }
        if (it + 1 < pcnt) STAGEB(ntj, Bbuf[cur ^ 1]);  // flies under compute
        if (csi != asi) { LOADA(csi); asi = csi; }      // rare slab crossing

#pragma unroll
        for (int m = 0; m < 4; ++m)
#pragma unroll
            for (int n = 0; n < 4; ++n) acc[m][n] = (f32x4){0.f, 0.f, 0.f, 0.f};

        COMPUTEP(Bbuf[cur]);

        // ---- epilogue for this pair (S1 only; S2 closed-form) ----
        const float* sqB = sq + ctj * TIL + wc * 64 + (lane & 15);
        float nb[4];
#pragma unroll
        for (int n = 0; n < 4; ++n) nb[n] = sqB[n * 16];

        if (csi != ctj) {
#pragma unroll
            for (int m = 0; m < 4; ++m) {
                const float4 v = na4[m];
#pragma unroll
                for (int n = 0; n < 4; ++n) {
                    sOa += fsqrt(fmaxf(fmaf(-2.f, acc[m][n][0], v.x + nb[n]), 0.f));
                    sOb += fsqrt(fmaxf(fmaf(-2.f, acc[m][n][1], v.y + nb[n]), 0.f));
                    sOc += fsqrt(fmaxf(fmaf(-2.f, acc[m][n][2], v.z + nb[n]), 0.f));
                    sOd += fsqrt(fmaxf(fmaf(-2.f, acc[m][n][3], v.w + nb[n]), 0.f));
                }
            }
        } else {
#pragma unroll
            for (int m = 0; m < 4; ++m) {
                const float4 v = na4[m];
                const float nav[4] = {v.x, v.y, v.z, v.w};
#pragma unroll
                for (int n = 0; n < 4; ++n) {
                    const int col = wc * 64 + n * 16 + (lane & 15);
#pragma unroll
                    for (int r = 0; r < 4; ++r) {
                        const int row = wr * 64 + m * 16 + (lane >> 4) * 4 + r;
                        float d = fmaxf(fmaf(-2.f, acc[m][n][r], nav[r] + nb[n]), 0.f);
                        if (row == col) d = 0.f;   // exact-0 diagonal like ref
                        sD += fsqrt(d);
                    }
                }
            }
        }

        __syncthreads();     // stage(next) drained + Bbuf[cur] free for reuse
        cur ^= 1;
        csi = nsi; ctj = ntj;
    }

    float s1 = sD + 2.f * ((sOa + sOb) + (sOc + sOd));
#pragma unroll
    for (int off = 1; off < 64; off <<= 1) s1 += __shfl_xor(s1, off);
    if (lane == 0) rr[wv] = (double)s1;
    __syncthreads();
    if (tid == 0) partials[b] = (rr[0] + rr[1]) + (rr[2] + rr[3]);
#undef LOADA
#undef STAGEB
#undef COMPUTEP
}

// ---- finalize: S1 reduce + closed-form S2 (deterministic fp64) ----
__global__ __launch_bounds__(256)
void ph_finalize(const double* __restrict__ partials, const float* __restrict__ sq,
                 const float* __restrict__ cs_part, float* __restrict__ out)
{
    __shared__ double r1[256], r2[256], r3[128];
    const int tid = threadIdx.x;
    double s1 = 0.0;
    for (int i = tid; i < NBLKS; i += 256) s1 += partials[i];
    double sn = 0.0;
    for (int k = 0; k < NPTS / 256; ++k) sn += (double)sq[tid + k * 256];
    r1[tid] = s1; r2[tid] = sn;
    if (tid < DIM) {                       // column sum over 256 prep blocks
        double c = 0.0;
        for (int b = 0; b < NPREP; ++b) c += (double)cs_part[b * DIM + tid];
        r3[tid] = c * c;                   // squared component
    }
    __syncthreads();
    for (int off = 128; off > 0; off >>= 1) {
        if (tid < off) { r1[tid] += r1[tid + off]; r2[tid] += r2[tid + off]; }
        __syncthreads();
    }
    for (int off = 64; off > 0; off >>= 1) {
        if (tid < off) r3[tid] += r3[tid + off];
        __syncthreads();
    }
    if (tid == 0) {
        const double M    = (double)NPTS * (double)NPTS;
        const double S1   = r1[0];
        const double S2   = 2.0 * (double)NPTS * r2[0] - 2.0 * r3[0];
        const double mean = S1 / M;
        double var = (S2 - S1 * S1 / M) / (M - 1.0);
        if (var < 0.0) var = 0.0;
        out[0] = (float)(sqrt(var) / (mean + 1e-8));
    }
}

// ---------------- fp32 fallback (only if ws too small) ----------------
#define LSTR 132
__global__ __launch_bounds__(256)
void ph_pair_kernel(const float* __restrict__ x, double* __restrict__ partials)
{
    const int bi  = blockIdx.y;
    const int bj  = blockIdx.x;
    const int tid = threadIdx.x;
    const int flat = bi * NTILES + bj;
    if (bj < bi) {
        if (tid == 0) { partials[2*flat] = 0.0; partials[2*flat+1] = 0.0; }
        return;
    }
    __shared__ __align__(16) float As[128 * LSTR];
    __shared__ __align__(16) float Bs[128 * LSTR];
    __shared__ float  nA[128];
    __shared__ float  nB[128];
    __shared__ double red1[256];
    __shared__ double red2[256];
    const float* Ab = x + (size_t)bi * 128 * DIM;
    const float* Bb = x + (size_t)bj * 128 * DIM;
#pragma unroll
    for (int it = 0; it < 16; ++it) {
        const int e   = (tid + it * 256) * 4;
        const int row = e >> 7;
        const int k   = e & 127;
        float4 va = *reinterpret_cast<const float4*>(Ab + e);
        As[(k+0)*LSTR + row] = va.x; As[(k+1)*LSTR + row] = va.y;
        As[(k+2)*LSTR + row] = va.z; As[(k+3)*LSTR + row] = va.w;
        float4 vb = *reinterpret_cast<const float4*>(Bb + e);
        Bs[(k+0)*LSTR + row] = vb.x; Bs[(k+1)*LSTR + row] = vb.y;
        Bs[(k+2)*LSTR + row] = vb.z; Bs[(k+3)*LSTR + row] = vb.w;
    }
    __syncthreads();
    if (tid < 128) {
        float s = 0.f;
#pragma unroll 8
        for (int k = 0; k < DIM; ++k) { float v = As[k*LSTR + tid]; s = fmaf(v, v, s); }
        nA[tid] = s;
    } else {
        const int r = tid - 128;
        float s = 0.f;
#pragma unroll 8
        for (int k = 0; k < DIM; ++k) { float v = Bs[k*LSTR + r]; s = fmaf(v, v, s); }
        nB[r] = s;
    }
    __syncthreads();
    const int tx = tid & 15, ty = tid >> 4;
    const int ra = ty * 8, cb = tx * 8;
    float acc[8][8];
#pragma unroll
    for (int r = 0; r < 8; ++r)
#pragma unroll
        for (int c = 0; c < 8; ++c) acc[r][c] = 0.f;
#pragma unroll 4
    for (int k = 0; k < DIM; ++k) {
        const float4 a0 = *reinterpret_cast<const float4*>(&As[k*LSTR + ra]);
        const float4 a1 = *reinterpret_cast<const float4*>(&As[k*LSTR + ra + 4]);
        const float4 b0 = *reinterpret_cast<const float4*>(&Bs[k*LSTR + cb]);
        const float4 b1 = *reinterpret_cast<const float4*>(&Bs[k*LSTR + cb + 4]);
        const float a[8] = {a0.x,a0.y,a0.z,a0.w,a1.x,a1.y,a1.z,a1.w};
        const float b[8] = {b0.x,b0.y,b0.z,b0.w,b1.x,b1.y,b1.z,b1.w};
#pragma unroll
        for (int r = 0; r < 8; ++r)
#pragma unroll
            for (int c = 0; c < 8; ++c)
                acc[r][c] = fmaf(a[r], b[c], acc[r][c]);
    }
    double s1 = 0.0, s2 = 0.0;
    const int gi0 = bi*128 + ra, gj0 = bj*128 + cb;
#pragma unroll
    for (int r = 0; r < 8; ++r) {
#pragma unroll
        for (int c = 0; c < 8; ++c) {
            float d2 = nA[ra+r] + nB[cb+c] - 2.0f * acc[r][c];
            d2 = fmaxf(d2, 0.0f);
            if (gi0 + r == gj0 + c) d2 = 0.0f;
            s1 += (double)sqrtf(d2);
            s2 += (double)d2;
        }
    }
    const double w = (bi == bj) ? 1.0 : 2.0;
    s1 *= w; s2 *= w;
    red1[tid] = s1; red2[tid] = s2;
    __syncthreads();
    for (int off = 128; off > 0; off >>= 1) {
        if (tid < off) { red1[tid] += red1[tid+off]; red2[tid] += red2[tid+off]; }
        __syncthreads();
    }
    if (tid == 0) { partials[2*flat] = red1[0]; partials[2*flat+1] = red2[0]; }
}

__global__ __launch_bounds__(256)
void ph_finalize_sq(const double* __restrict__ partials, float* __restrict__ out)
{
    __shared__ double r1[256], r2[256];
    const int tid = threadIdx.x;
    double s1 = 0.0, s2 = 0.0;
    for (int i = tid; i < NTOTSQ; i += 256) { s1 += partials[2*i]; s2 += partials[2*i+1]; }
    r1[tid] = s1; r2[tid] = s2;
    __syncthreads();
    for (int off = 128; off > 0; off >>= 1) {
        if (tid < off) { r1[tid] += r1[tid+off]; r2[tid] += r2[tid+off]; }
        __syncthreads();
    }
    if (tid == 0) {
        const double M    = (double)NPTS * (double)NPTS;
        const double mean = r1[0] / M;
        double var = (r2[0] - r1[0]*r1[0]/M) / (M - 1.0);
        if (var < 0.0) var = 0.0;
        out[0] = (float)(sqrt(var) / (mean + 1e-8));
    }
}

extern "C" void kernel_launch(void* const* d_in, const int* in_sizes, int n_in,
                              void* d_out, int out_size, void* d_ws, size_t ws_size,
                              hipStream_t stream)
{
    const float* x = (const float*)d_in[0];   // [8192, 128] fp32
    float* out     = (float*)d_out;

    // ws layout: xb bf16 (2MB) | sq (32KB) | cs_part (128KB) | partials (512*8)
    const size_t XB_OFF = 0;
    const size_t SQ_OFF = (size_t)NPTS * DIM * sizeof(ushort);   // 2 MB
    const size_t CS_OFF = SQ_OFF + NPTS * sizeof(float);
    const size_t PT_OFF = CS_OFF + (size_t)NPREP * DIM * sizeof(float);
    const size_t NEEDED = PT_OFF + (size_t)NBLKS * sizeof(double);

    if (ws_size >= NEEDED) {
        ushort* xb       = (ushort*)((char*)d_ws + XB_OFF);
        float*  sq       = (float*) ((char*)d_ws + SQ_OFF);
        float*  cs_part  = (float*) ((char*)d_ws + CS_OFF);
        double* partials = (double*)((char*)d_ws + PT_OFF);

        ph_prep<<<NPREP, 256, 0, stream>>>(x, xb, sq, cs_part);
        ph_gram<<<NBLKS, 256, 0, stream>>>(xb, sq, partials);
        ph_finalize<<<1, 256, 0, stream>>>(partials, sq, cs_part, out);
    } else {
        double* partials = (double*)d_ws;
        ph_pair_kernel<<<dim3(NTILES, NTILES), 256, 0, stream>>>(x, partials);
        ph_finalize_sq<<<1, 256, 0, stream>>>(partials, out);
    }
}